// Round 11
// baseline (280.169 us; speedup 1.0000x reference)
//
#include <hip/hip_runtime.h>
#include <hip/hip_bf16.h>

// MambaBlock: B=2, L=1024, dim=1024, d_inner=2048, DT_RANK=64, D_STATE=16
// Inputs fp32, output fp32. Intermediates xz/u/dt/y in bf16; scan state fp32.
// MFMA GEMMs: 128x64 tile, BK=32, dbuf single-barrier global_load_lds K-loop.
//
// ws layout (float units):
//   xn_b  (bf16 2048x1024) : @0          1,048,576
//   xz_b  (bf16 2048x4096) : @1,048,576  4,194,304   } opart (fp32 4x2,097,152)
//   u_b   (bf16 2048x2048) : @5,242,880  2,097,152   }   aliases xz_b..dt_b
//   xdbl  (fp32 2048x96)   : @7,340,032    196,608   }   after scan_part2
//   dt_b  (bf16 2048x2048) : @7,536,640  2,097,152   }
//   hpart (fp32 32x65536)  : @9,633,792  2,097,152   } xpart (16x196608) aliases
//   Aprod (fp32 32x65536)  : @11,730,944 2,097,152   }   hpart..hinit pre-scan
//   hinit (fp32 32x65536)  : @13,828,096 2,097,152
//   y_b   (bf16 2048x2048) : @15,925,248 2,097,152
//   w_in_b (bf16)          : @18,022,400 2,097,152
//   w_out_b(bf16)          : @20,119,552 1,048,576
//   w_dt_b (bf16)          : @21,168,128    65,536
//   dtr_b  (bf16)          : @21,233,664    65,536
// total 21,299,200 fu = 85.2 MB (R10 used 97.2 MB OK)

#define LC 32
#define NCHUNK 32

typedef short bf16x8 __attribute__((ext_vector_type(8)));
typedef float f32x4  __attribute__((ext_vector_type(4)));

static __device__ __forceinline__ float siluf(float x) { return x / (1.f + __expf(-x)); }
static __device__ __forceinline__ unsigned short f2bf(float f) {
    unsigned int u = __float_as_uint(f);
    unsigned int r = (u + 0x7fffu + ((u >> 16) & 1u)) >> 16;
    return (unsigned short)r;
}
static __device__ __forceinline__ float bfb(unsigned short u) {
    return __uint_as_float(((unsigned int)u) << 16);
}
// async global->LDS, 16 B per lane; LDS dest = wave-uniform base + lane*16
static __device__ __forceinline__ void gload_lds16(const void* g, void* l) {
    __builtin_amdgcn_global_load_lds(
        (const __attribute__((address_space(1))) void*)g,
        (__attribute__((address_space(3))) void*)l, 16, 0, 0);
}

// ---------------- fp32 -> bf16 convert: all three weights in one launch ----------------
__global__ __launch_bounds__(256) void f2b_all(
    const float* __restrict__ w_in,  unsigned short* __restrict__ w_in_b,
    const float* __restrict__ w_out, unsigned short* __restrict__ w_out_b,
    const float* __restrict__ w_dt,  unsigned short* __restrict__ w_dt_b)
{
    int i = blockIdx.x * 256 + threadIdx.x;
    const float* in; unsigned short* outp; int j;
    if (i < 1048576)      { in = w_in;  outp = w_in_b;  j = i; }
    else if (i < 1572864) { in = w_out; outp = w_out_b; j = i - 1048576; }
    else if (i < 1605632) { in = w_dt;  outp = w_dt_b;  j = i - 1572864; }
    else return;
    float4 v = reinterpret_cast<const float4*>(in)[j];
    ushort4 o = { f2bf(v.x), f2bf(v.y), f2bf(v.z), f2bf(v.w) };
    reinterpret_cast<ushort4*>(outp)[j] = o;
}

// ---------------- LayerNorm -> bf16 ----------------
__global__ __launch_bounds__(256) void ln_kernel(
    const float* __restrict__ x,
    const float* __restrict__ w,
    const float* __restrict__ bias,
    unsigned short* __restrict__ xn)
{
    int m = blockIdx.x, tid = threadIdx.x;
    const float4* xr = reinterpret_cast<const float4*>(x) + (size_t)m * 256;
    float4 r = xr[tid];
    float f0 = r.x, f1 = r.y, f2 = r.z, f3 = r.w;
    float s  = f0 + f1 + f2 + f3;
    float s2 = f0*f0 + f1*f1 + f2*f2 + f3*f3;
    #pragma unroll
    for (int off = 32; off > 0; off >>= 1) {
        s  += __shfl_down(s, off);
        s2 += __shfl_down(s2, off);
    }
    __shared__ float red[8];
    if ((tid & 63) == 0) { red[tid >> 6] = s; red[4 + (tid >> 6)] = s2; }
    __syncthreads();
    float st = red[0] + red[1] + red[2] + red[3];
    float qt = red[4] + red[5] + red[6] + red[7];
    float mu   = st * (1.f / 1024.f);
    float var  = qt * (1.f / 1024.f) - mu * mu;
    float rstd = rsqrtf(var + 1e-5f);
    float4 wv = reinterpret_cast<const float4*>(w)[tid];
    float4 bv = reinterpret_cast<const float4*>(bias)[tid];
    ushort4 o = { f2bf((f0 - mu) * rstd * wv.x + bv.x),
                  f2bf((f1 - mu) * rstd * wv.y + bv.y),
                  f2bf((f2 - mu) * rstd * wv.z + bv.z),
                  f2bf((f3 - mu) * rstd * wv.w + bv.w) };
    reinterpret_cast<ushort4*>(xn + (size_t)m * 1024)[tid] = o;
}

// ---------------- bf16 MFMA GEMM-NT, 128x64 tile, dbuf single-barrier K-loop -------
// ep: 0 = fp32 raw -> C; 1 = softplus(acc+bias[n]) -> Cb bf16; 3 = raw -> Cb bf16
__global__ __launch_bounds__(256) void gemm_bf16_nt(
    const unsigned short* __restrict__ A, int lda,
    const unsigned short* __restrict__ B, int ldb,
    int Kslice,
    float* __restrict__ C, unsigned short* __restrict__ Cb, int ldc,
    const float* __restrict__ bias,
    int ep, size_t Cstride)
{
    __shared__ short As[2 * 128 * 32];   // 16 KB
    __shared__ short Bs[2 * 64 * 32];    //  8 KB
    int tid = threadIdx.x;
    int z = blockIdx.z;
    A += (size_t)z * Kslice;
    B += (size_t)z * Kslice;
    C += (size_t)z * Cstride;
    int m0 = blockIdx.y * 128, n0 = blockIdx.x * 64;
    int lane = tid & 63, wave = tid >> 6;
    int wm = (wave >> 1) * 64, wn = (wave & 1) * 32;
    int frow = lane & 15, fq = lane >> 4;

    f32x4 acc[4][2] = {};

    int lrow = lane >> 2;
    int scol = (lane & 3) * 8;
    const unsigned short* AgL = A + (size_t)(m0 + wave * 32 + lrow) * lda + scol;
    const unsigned short* BgL = B + (size_t)(n0 + wave * 16 + lrow) * ldb + scol;
    int aoff = (wave * 32) * 32;
    int boff = (wave * 16) * 32;

    gload_lds16(AgL,                      As + aoff);
    gload_lds16(AgL + (size_t)16 * lda,   As + aoff + 16 * 32);
    gload_lds16(BgL,                      Bs + boff);

    int cur = 0;
    for (int k0 = 0; k0 < Kslice; k0 += 32) {
        __syncthreads();
        int nk = k0 + 32;
        if (nk < Kslice) {
            int nxt = cur ^ 1;
            gload_lds16(AgL + nk,                     As + nxt * 4096 + aoff);
            gload_lds16(AgL + (size_t)16 * lda + nk,  As + nxt * 4096 + aoff + 16 * 32);
            gload_lds16(BgL + nk,                     Bs + nxt * 2048 + boff);
        }
        const short* Ac = As + cur * 4096;
        const short* Bc = Bs + cur * 2048;
        bf16x8 af[4], bfr[2];
        #pragma unroll
        for (int i = 0; i < 4; ++i)
            af[i] = *reinterpret_cast<const bf16x8*>(Ac + (wm + i * 16 + frow) * 32 + fq * 8);
        #pragma unroll
        for (int j = 0; j < 2; ++j)
            bfr[j] = *reinterpret_cast<const bf16x8*>(Bc + (wn + j * 16 + frow) * 32 + fq * 8);
        #pragma unroll
        for (int i = 0; i < 4; ++i)
            #pragma unroll
            for (int j = 0; j < 2; ++j)
                acc[i][j] = __builtin_amdgcn_mfma_f32_16x16x32_bf16(af[i], bfr[j], acc[i][j], 0, 0, 0);
        cur ^= 1;
    }

    int cn = lane & 15, rq = (lane >> 4) * 4;
    #pragma unroll
    for (int i = 0; i < 4; ++i) {
        #pragma unroll
        for (int j = 0; j < 2; ++j) {
            #pragma unroll
            for (int r = 0; r < 4; ++r) {
                int row = m0 + wm + i * 16 + rq + r;
                int col = n0 + wn + j * 16 + cn;
                float v = acc[i][j][r];
                if (ep == 0) {
                    C[(size_t)row * ldc + col] = v;
                } else if (ep == 1) {
                    v += bias[col];
                    v = (v > 20.f) ? v : log1pf(__expf(v));
                    Cb[(size_t)row * ldc + col] = f2bf(v);
                } else {
                    Cb[(size_t)row * ldc + col] = f2bf(v);
                }
            }
        }
    }
}

// ---------------- out = x + sum_z part[z] ----------------
__global__ __launch_bounds__(256) void out_reduce(
    const float* __restrict__ part, const float* __restrict__ x,
    float* __restrict__ out)
{
    int i = blockIdx.x * 256 + threadIdx.x;
    float4 s = reinterpret_cast<const float4*>(x)[i];
    #pragma unroll
    for (int z = 0; z < 4; ++z) {
        float4 p = reinterpret_cast<const float4*>(part + (size_t)z * 2097152)[i];
        s.x += p.x; s.y += p.y; s.z += p.z; s.w += p.w;
    }
    reinterpret_cast<float4*>(out)[i] = s;
}

// ---------------- xproj split-K: A = u (bf16), B = w_xproj (fp32) ----------------
__global__ __launch_bounds__(256) void xproj_splitk(
    const unsigned short* __restrict__ A,
    const float* __restrict__ B,
    float* __restrict__ part)
{
    __shared__ float As[16][68];
    __shared__ float Bs[16][100];
    int tid = threadIdx.x;
    int m0 = blockIdx.x * 64;
    int k0 = blockIdx.y * 128;
    int tx = tid & 15;
    int ty = tid >> 4;
    float acc[4][6] = {};
    int arow = tid >> 2, akg = (tid & 3) << 2;
    int brow1 = (256 + tid) >> 2, bkg1 = ((256 + tid) & 3) << 2;

    for (int ks = 0; ks < 128; ks += 16) {
        ushort4 au = *reinterpret_cast<const ushort4*>(A + (size_t)(m0 + arow) * 2048 + k0 + ks + akg);
        float4 av = make_float4(bfb(au.x), bfb(au.y), bfb(au.z), bfb(au.w));
        float4 bv0 = make_float4(0.f, 0.f, 0.f, 0.f), bv1 = bv0;
        if (arow < 96)  bv0 = *reinterpret_cast<const float4*>(B + (size_t)arow * 2048 + k0 + ks + akg);
        if (brow1 < 96) bv1 = *reinterpret_cast<const float4*>(B + (size_t)brow1 * 2048 + k0 + ks + bkg1);
        __syncthreads();
        As[akg + 0][arow] = av.x; As[akg + 1][arow] = av.y;
        As[akg + 2][arow] = av.z; As[akg + 3][arow] = av.w;
        if (arow < 96) {
            Bs[akg + 0][arow] = bv0.x; Bs[akg + 1][arow] = bv0.y;
            Bs[akg + 2][arow] = bv0.z; Bs[akg + 3][arow] = bv0.w;
        }
        if (brow1 < 96) {
            Bs[bkg1 + 0][brow1] = bv1.x; Bs[bkg1 + 1][brow1] = bv1.y;
            Bs[bkg1 + 2][brow1] = bv1.z; Bs[bkg1 + 3][brow1] = bv1.w;
        }
        __syncthreads();
        #pragma unroll
        for (int k = 0; k < 16; ++k) {
            float aa[4], bb[6];
            #pragma unroll
            for (int i = 0; i < 4; ++i) aa[i] = As[k][ty * 4 + i];
            #pragma unroll
            for (int j = 0; j < 6; ++j) bb[j] = Bs[k][tx * 6 + j];
            #pragma unroll
            for (int i = 0; i < 4; ++i)
                #pragma unroll
                for (int j = 0; j < 6; ++j)
                    acc[i][j] = fmaf(aa[i], bb[j], acc[i][j]);
        }
    }
    float* p = part + (size_t)blockIdx.y * 196608;
    #pragma unroll
    for (int i = 0; i < 4; ++i)
        #pragma unroll
        for (int j = 0; j < 6; ++j)
            p[(size_t)(m0 + ty * 4 + i) * 96 + tx * 6 + j] = acc[i][j];
}

// reduce 16 partials -> xdbl fp32; also emit dt_r (cols<64) as bf16
__global__ __launch_bounds__(256) void xproj_reduce(
    const float* __restrict__ part, float* __restrict__ xdbl,
    unsigned short* __restrict__ dtr)
{
    int i = blockIdx.x * 256 + threadIdx.x;   // 196608
    float s = 0.f;
    #pragma unroll
    for (int sd = 0; sd < 16; ++sd) s += part[(size_t)sd * 196608 + i];
    xdbl[i] = s;
    int m = i / 96, col = i - m * 96;
    if (col < 64) dtr[(size_t)m * 64 + col] = f2bf(s);
}

// ---------------- Depthwise causal conv (width 4) + SiLU: bf16 in/out ----------------
__global__ __launch_bounds__(256) void conv_silu_kernel(
    const unsigned short* __restrict__ xz,
    const float* __restrict__ cw,
    const float* __restrict__ cb,
    unsigned short* __restrict__ u)
{
    int idx = blockIdx.x * 256 + threadIdx.x;
    int e = idx & 2047;
    int m = idx >> 11;
    int l = m & 1023;
    float acc = cb[e];
    #pragma unroll
    for (int k = 0; k < 4; ++k) {
        int ls = l - 3 + k;
        if (ls >= 0)
            acc += cw[e * 4 + k] * bfb(xz[(size_t)(m - 3 + k) * 4096 + e]);
    }
    u[(size_t)m * 2048 + e] = f2bf(siluf(acc));
}

// ---------------- Chunked selective scan: 4 states/lane, LC=32, depth-2 pipeline ----
__global__ __launch_bounds__(256) void scan_part1(
    const unsigned short* __restrict__ dt,
    const unsigned short* __restrict__ u,
    const float* __restrict__ xdbl,
    const float* __restrict__ a_log,
    float* __restrict__ hpart,
    float* __restrict__ Aprod)
{
    int tid = threadIdx.x;
    int ch = tid >> 2, ng = tid & 3;
    int bid = blockIdx.x;
    int c = bid & 31, et = (bid >> 5) & 31, b = bid >> 10;
    int e = et * 64 + ch;
    float4 al = *reinterpret_cast<const float4*>(a_log + e * 16 + ng * 4);
    float A0 = -__expf(al.x), A1 = -__expf(al.y), A2 = -__expf(al.z), A3 = -__expf(al.w);
    size_t rbase = (size_t)b * 1024 + c * LC;
    const unsigned short* dt_p = dt + rbase * 2048 + e;
    const unsigned short* u_p  = u  + rbase * 2048 + e;
    const float* b_p  = xdbl + rbase * 96 + 64 + ng * 4;
    float h0 = 0.f, h1 = 0.f, h2 = 0.f, h3 = 0.f;
    float P0 = 1.f, P1 = 1.f, P2 = 1.f, P3 = 1.f;
    float dt_c = bfb(dt_p[0]);
    float u_c  = bfb(u_p[0]);
    float4 B_c = *reinterpret_cast<const float4*>(b_p);
    #pragma unroll 4
    for (int l = 0; l < LC; ++l) {
        float dt_n = bfb(dt_p[(size_t)(l + 1) * 2048]);
        float u_n  = bfb(u_p[(size_t)(l + 1) * 2048]);
        float4 B_n = *reinterpret_cast<const float4*>(b_p + (size_t)(l + 1) * 96);
        float du = dt_c * u_c;
        float d0 = __expf(dt_c * A0), d1 = __expf(dt_c * A1);
        float d2 = __expf(dt_c * A2), d3 = __expf(dt_c * A3);
        h0 = fmaf(d0, h0, du * B_c.x); P0 *= d0;
        h1 = fmaf(d1, h1, du * B_c.y); P1 *= d1;
        h2 = fmaf(d2, h2, du * B_c.z); P2 *= d2;
        h3 = fmaf(d3, h3, du * B_c.w); P3 *= d3;
        dt_c = dt_n; u_c = u_n; B_c = B_n;
    }
    size_t oidx = (size_t)c * 65536 + ((size_t)b * 2048 + e) * 16 + ng * 4;
    *reinterpret_cast<float4*>(hpart + oidx) = make_float4(h0, h1, h2, h3);
    *reinterpret_cast<float4*>(Aprod + oidx) = make_float4(P0, P1, P2, P3);
}

__global__ __launch_bounds__(256) void scan_combine(
    const float* __restrict__ hpart,
    const float* __restrict__ Aprod,
    float* __restrict__ hinit)
{
    int t = (blockIdx.x * 256 + threadIdx.x) * 4;
    float4 h = make_float4(0.f, 0.f, 0.f, 0.f);
    #pragma unroll
    for (int c = 0; c < NCHUNK; ++c) {
        *reinterpret_cast<float4*>(hinit + (size_t)c * 65536 + t) = h;
        float4 P = *reinterpret_cast<const float4*>(Aprod + (size_t)c * 65536 + t);
        float4 hp = *reinterpret_cast<const float4*>(hpart + (size_t)c * 65536 + t);
        h.x = fmaf(P.x, h.x, hp.x);
        h.y = fmaf(P.y, h.y, hp.y);
        h.z = fmaf(P.z, h.z, hp.z);
        h.w = fmaf(P.w, h.w, hp.w);
    }
}

__global__ __launch_bounds__(256) void scan_part2(
    const unsigned short* __restrict__ dt,
    const unsigned short* __restrict__ u,
    const float* __restrict__ xdbl,
    const unsigned short* __restrict__ xz,
    const float* __restrict__ a_log,
    const float* __restrict__ d_skip,
    const float* __restrict__ hinit,
    unsigned short* __restrict__ y)
{
    int tid = threadIdx.x;
    int ch = tid >> 2, ng = tid & 3;
    int bid = blockIdx.x;
    int c = bid & 31, et = (bid >> 5) & 31, b = bid >> 10;
    int e = et * 64 + ch;
    float4 al = *reinterpret_cast<const float4*>(a_log + e * 16 + ng * 4);
    float A0 = -__expf(al.x), A1 = -__expf(al.y), A2 = -__expf(al.z), A3 = -__expf(al.w);
    float dsk = d_skip[e];
    size_t rbase = (size_t)b * 1024 + c * LC;
    const unsigned short* dt_p = dt + rbase * 2048 + e;
    const unsigned short* u_p  = u  + rbase * 2048 + e;
    const unsigned short* z_p  = xz + rbase * 4096 + 2048 + e;
    const float* bc_p = xdbl + rbase * 96 + 64 + ng * 4;
    unsigned short* y_p = y + rbase * 2048 + e;
    size_t oidx = (size_t)c * 65536 + ((size_t)b * 2048 + e) * 16 + ng * 4;
    float4 hi = *reinterpret_cast<const float4*>(hinit + oidx);
    float h0 = hi.x, h1 = hi.y, h2 = hi.z, h3 = hi.w;
    float dt_c = bfb(dt_p[0]);
    float u_c  = bfb(u_p[0]);
    float4 B_c = *reinterpret_cast<const float4*>(bc_p);
    float4 C_c = *reinterpret_cast<const float4*>(bc_p + 16);
    #pragma unroll 4
    for (int l = 0; l < LC; ++l) {
        float dt_n = bfb(dt_p[(size_t)(l + 1) * 2048]);
        float u_n  = bfb(u_p[(size_t)(l + 1) * 2048]);
        float4 B_n = *reinterpret_cast<const float4*>(bc_p + (size_t)(l + 1) * 96);
        float4 C_n = *reinterpret_cast<const float4*>(bc_p + (size_t)(l + 1) * 96 + 16);
        float du = dt_c * u_c;
        float d0 = __expf(dt_c * A0), d1 = __expf(dt_c * A1);
        float d2 = __expf(dt_c * A2), d3 = __expf(dt_c * A3);
        h0 = fmaf(d0, h0, du * B_c.x);
        h1 = fmaf(d1, h1, du * B_c.y);
        h2 = fmaf(d2, h2, du * B_c.z);
        h3 = fmaf(d3, h3, du * B_c.w);
        float p = h0 * C_c.x + h1 * C_c.y + h2 * C_c.z + h3 * C_c.w;
        p += __shfl_xor(p, 1);
        p += __shfl_xor(p, 2);
        if (ng == 0) {
            float zv = bfb(z_p[(size_t)l * 4096]);
            y_p[(size_t)l * 2048] = f2bf((p + u_c * dsk) * siluf(zv));
        }
        dt_c = dt_n; u_c = u_n; B_c = B_n; C_c = C_n;
    }
}

extern "C" void kernel_launch(void* const* d_in, const int* in_sizes, int n_in,
                              void* d_out, int out_size, void* d_ws, size_t ws_size,
                              hipStream_t stream) {
    const float* x       = (const float*)d_in[0];
    const float* ln_w    = (const float*)d_in[1];
    const float* ln_b    = (const float*)d_in[2];
    const float* w_in    = (const float*)d_in[3];
    const float* conv_w  = (const float*)d_in[4];
    const float* conv_b  = (const float*)d_in[5];
    const float* w_xproj = (const float*)d_in[6];
    const float* w_dt    = (const float*)d_in[7];
    const float* b_dt    = (const float*)d_in[8];
    const float* a_log   = (const float*)d_in[9];
    const float* d_skip  = (const float*)d_in[10];
    const float* w_out   = (const float*)d_in[11];
    float* out = (float*)d_out;

    float* ws = (float*)d_ws;
    unsigned short* xn_b    = (unsigned short*)(ws);
    unsigned short* xz_b    = (unsigned short*)(ws + 1048576);
    unsigned short* u_b     = (unsigned short*)(ws + 5242880);
    float* xdbl  = ws + 7340032;
    unsigned short* dt_b    = (unsigned short*)(ws + 7536640);
    float* hpart = ws + 9633792;
    float* Aprod = ws + 11730944;
    float* hinit = ws + 13828096;
    unsigned short* y_b     = (unsigned short*)(ws + 15925248);
    unsigned short* w_in_b  = (unsigned short*)(ws + 18022400);
    unsigned short* w_out_b = (unsigned short*)(ws + 20119552);
    unsigned short* w_dt_b  = (unsigned short*)(ws + 21168128);
    unsigned short* dtr_b   = (unsigned short*)(ws + 21233664);
    float* xpart = ws + 9633792;    // aliases hpart..hinit (dead until scan)
    float* opart = ws + 1048576;    // aliases xz_b..dt_b (dead after part2)

    // 0. all weight converts in one launch
    f2b_all<<<6272, 256, 0, stream>>>(w_in, w_in_b, w_out, w_out_b, w_dt, w_dt_b);
    // 1. LayerNorm -> bf16
    ln_kernel<<<2048, 256, 0, stream>>>(x, ln_w, ln_b, xn_b);
    // 2. xz = xn @ w_in^T  (2048 x 4096 x 1024)  MFMA -> bf16
    gemm_bf16_nt<<<dim3(64, 16, 1), 256, 0, stream>>>(xn_b, 1024, w_in_b, 1024, 1024,
                                                      nullptr, xz_b, 4096, nullptr, 3, 0);
    // 3. depthwise conv + silu -> u (bf16)
    conv_silu_kernel<<<16384, 256, 0, stream>>>(xz_b, conv_w, conv_b, u_b);
    // 4. x_dbl = u @ w_xproj^T  (2048 x 96 x 2048)  fp32 split-K (A bf16)
    xproj_splitk<<<dim3(32, 16), 256, 0, stream>>>(u_b, w_xproj, xpart);
    xproj_reduce<<<768, 256, 0, stream>>>(xpart, xdbl, dtr_b);
    // 5. dt = softplus(dt_r @ w_dt^T + b_dt)  MFMA -> bf16
    gemm_bf16_nt<<<dim3(32, 16, 1), 256, 0, stream>>>(dtr_b, 64, w_dt_b, 64, 64,
                                                      nullptr, dt_b, 2048, b_dt, 1, 0);
    // 6. chunked selective scan (LC=32, 32 chunks) -> y (bf16)
    scan_part1<<<2048, 256, 0, stream>>>(dt_b, u_b, xdbl, a_log, hpart, Aprod);
    scan_combine<<<64, 256, 0, stream>>>(hpart, Aprod, hinit);
    scan_part2<<<2048, 256, 0, stream>>>(dt_b, u_b, xdbl, xz_b, a_log, d_skip, hinit, y_b);
    // 7. out-proj split-K x4 (fp32 partials) + reduce(+residual)
    gemm_bf16_nt<<<dim3(16, 16, 4), 256, 0, stream>>>(y_b, 2048, w_out_b, 2048, 512,
                                                      opart, nullptr, 1024, nullptr, 0, 2097152);
    out_reduce<<<2048, 256, 0, stream>>>(opart, x, out);
}

// Round 12
// 275.863 us; speedup vs baseline: 1.0156x; 1.0156x over previous
//
#include <hip/hip_runtime.h>
#include <hip/hip_bf16.h>

// MambaBlock: B=2, L=1024, dim=1024, d_inner=2048, DT_RANK=64, D_STATE=16
// Inputs fp32, output fp32. Intermediates xz/u/dt/y bf16; scan state fp32.
// MFMA GEMMs: 128x64 tile, BK=32, dbuf single-barrier global_load_lds K-loop.
// Scan: LC=16, NCHUNK=64 (4096 blocks = 4 waves/SIMD).
//
// ws layout (float units):
//   xn_b  (bf16 2048x1024) : @0          1,048,576
//   xz_b  (bf16 2048x4096) : @1,048,576  4,194,304   } opart (fp32 4x2,097,152)
//   u_b   (bf16 2048x2048) : @5,242,880  2,097,152   }   aliases xz_b..dt_b
//   xdbl  (fp32 2048x96)   : @7,340,032    196,608   }   after scan_part2
//   dt_b  (bf16 2048x2048) : @7,536,640  2,097,152   }
//   hpart (fp32 64x65536)  : @9,633,792  4,194,304   } xpart (16x196608=3.1M)
//   Aprod (fp32 64x65536)  : @13,828,096 4,194,304   }   aliases hpart pre-scan
//   hinit (fp32 64x65536)  : @18,022,400 4,194,304
//   y_b   (bf16 2048x2048) : @22,216,704 2,097,152
//   w_in_b (bf16)          : @24,313,856 2,097,152
//   w_out_b(bf16)          : @26,411,008 1,048,576
//   w_dt_b (bf16)          : @27,459,584    65,536
//   dtr_b  (bf16)          : @27,525,120    65,536
// total 27,590,656 fu = 110 MB (ws = 256 MiB)

#define LC 16
#define NCHUNK 64

typedef short bf16x8 __attribute__((ext_vector_type(8)));
typedef float f32x4  __attribute__((ext_vector_type(4)));

static __device__ __forceinline__ float siluf(float x) { return x / (1.f + __expf(-x)); }
static __device__ __forceinline__ unsigned short f2bf(float f) {
    unsigned int u = __float_as_uint(f);
    unsigned int r = (u + 0x7fffu + ((u >> 16) & 1u)) >> 16;
    return (unsigned short)r;
}
static __device__ __forceinline__ float bfb(unsigned short u) {
    return __uint_as_float(((unsigned int)u) << 16);
}
// async global->LDS, 16 B per lane; LDS dest = wave-uniform base + lane*16
static __device__ __forceinline__ void gload_lds16(const void* g, void* l) {
    __builtin_amdgcn_global_load_lds(
        (const __attribute__((address_space(1))) void*)g,
        (__attribute__((address_space(3))) void*)l, 16, 0, 0);
}

// ---------------- fused setup: weight converts + LayerNorm ----------------
// blocks [0,6272): w_in/w_out/w_dt fp32->bf16;  blocks [6272,8320): LN row m
__global__ __launch_bounds__(256) void setup_kernel(
    const float* __restrict__ w_in,  unsigned short* __restrict__ w_in_b,
    const float* __restrict__ w_out, unsigned short* __restrict__ w_out_b,
    const float* __restrict__ w_dt,  unsigned short* __restrict__ w_dt_b,
    const float* __restrict__ x,
    const float* __restrict__ ln_w,
    const float* __restrict__ ln_b,
    unsigned short* __restrict__ xn)
{
    int bid = blockIdx.x, tid = threadIdx.x;
    if (bid < 6272) {
        int i = bid * 256 + tid;
        const float* in; unsigned short* outp; int j;
        if (i < 1048576)      { in = w_in;  outp = w_in_b;  j = i; }
        else if (i < 1572864) { in = w_out; outp = w_out_b; j = i - 1048576; }
        else if (i < 1605632) { in = w_dt;  outp = w_dt_b;  j = i - 1572864; }
        else return;
        float4 v = reinterpret_cast<const float4*>(in)[j];
        ushort4 o = { f2bf(v.x), f2bf(v.y), f2bf(v.z), f2bf(v.w) };
        reinterpret_cast<ushort4*>(outp)[j] = o;
        return;
    }
    int m = bid - 6272;
    const float4* xr = reinterpret_cast<const float4*>(x) + (size_t)m * 256;
    float4 r = xr[tid];
    float f0 = r.x, f1 = r.y, f2 = r.z, f3 = r.w;
    float s  = f0 + f1 + f2 + f3;
    float s2 = f0*f0 + f1*f1 + f2*f2 + f3*f3;
    #pragma unroll
    for (int off = 32; off > 0; off >>= 1) {
        s  += __shfl_down(s, off);
        s2 += __shfl_down(s2, off);
    }
    __shared__ float red[8];
    if ((tid & 63) == 0) { red[tid >> 6] = s; red[4 + (tid >> 6)] = s2; }
    __syncthreads();
    float st = red[0] + red[1] + red[2] + red[3];
    float qt = red[4] + red[5] + red[6] + red[7];
    float mu   = st * (1.f / 1024.f);
    float var  = qt * (1.f / 1024.f) - mu * mu;
    float rstd = rsqrtf(var + 1e-5f);
    float4 wv = reinterpret_cast<const float4*>(ln_w)[tid];
    float4 bv = reinterpret_cast<const float4*>(ln_b)[tid];
    ushort4 o = { f2bf((f0 - mu) * rstd * wv.x + bv.x),
                  f2bf((f1 - mu) * rstd * wv.y + bv.y),
                  f2bf((f2 - mu) * rstd * wv.z + bv.z),
                  f2bf((f3 - mu) * rstd * wv.w + bv.w) };
    reinterpret_cast<ushort4*>(xn + (size_t)m * 1024)[tid] = o;
}

// ---------------- bf16 MFMA GEMM-NT, 128x64 tile, dbuf single-barrier K-loop -------
// ep: 0 = fp32 raw -> C; 1 = softplus(acc+bias[n]) -> Cb bf16; 3 = raw -> Cb bf16
__global__ __launch_bounds__(256) void gemm_bf16_nt(
    const unsigned short* __restrict__ A, int lda,
    const unsigned short* __restrict__ B, int ldb,
    int Kslice,
    float* __restrict__ C, unsigned short* __restrict__ Cb, int ldc,
    const float* __restrict__ bias,
    int ep, size_t Cstride)
{
    __shared__ short As[2 * 128 * 32];   // 16 KB
    __shared__ short Bs[2 * 64 * 32];    //  8 KB
    int tid = threadIdx.x;
    int z = blockIdx.z;
    A += (size_t)z * Kslice;
    B += (size_t)z * Kslice;
    C += (size_t)z * Cstride;
    int m0 = blockIdx.y * 128, n0 = blockIdx.x * 64;
    int lane = tid & 63, wave = tid >> 6;
    int wm = (wave >> 1) * 64, wn = (wave & 1) * 32;
    int frow = lane & 15, fq = lane >> 4;

    f32x4 acc[4][2] = {};

    int lrow = lane >> 2;
    int scol = (lane & 3) * 8;
    const unsigned short* AgL = A + (size_t)(m0 + wave * 32 + lrow) * lda + scol;
    const unsigned short* BgL = B + (size_t)(n0 + wave * 16 + lrow) * ldb + scol;
    int aoff = (wave * 32) * 32;
    int boff = (wave * 16) * 32;

    gload_lds16(AgL,                      As + aoff);
    gload_lds16(AgL + (size_t)16 * lda,   As + aoff + 16 * 32);
    gload_lds16(BgL,                      Bs + boff);

    int cur = 0;
    for (int k0 = 0; k0 < Kslice; k0 += 32) {
        __syncthreads();
        int nk = k0 + 32;
        if (nk < Kslice) {
            int nxt = cur ^ 1;
            gload_lds16(AgL + nk,                     As + nxt * 4096 + aoff);
            gload_lds16(AgL + (size_t)16 * lda + nk,  As + nxt * 4096 + aoff + 16 * 32);
            gload_lds16(BgL + nk,                     Bs + nxt * 2048 + boff);
        }
        const short* Ac = As + cur * 4096;
        const short* Bc = Bs + cur * 2048;
        bf16x8 af[4], bfr[2];
        #pragma unroll
        for (int i = 0; i < 4; ++i)
            af[i] = *reinterpret_cast<const bf16x8*>(Ac + (wm + i * 16 + frow) * 32 + fq * 8);
        #pragma unroll
        for (int j = 0; j < 2; ++j)
            bfr[j] = *reinterpret_cast<const bf16x8*>(Bc + (wn + j * 16 + frow) * 32 + fq * 8);
        #pragma unroll
        for (int i = 0; i < 4; ++i)
            #pragma unroll
            for (int j = 0; j < 2; ++j)
                acc[i][j] = __builtin_amdgcn_mfma_f32_16x16x32_bf16(af[i], bfr[j], acc[i][j], 0, 0, 0);
        cur ^= 1;
    }

    int cn = lane & 15, rq = (lane >> 4) * 4;
    #pragma unroll
    for (int i = 0; i < 4; ++i) {
        #pragma unroll
        for (int j = 0; j < 2; ++j) {
            #pragma unroll
            for (int r = 0; r < 4; ++r) {
                int row = m0 + wm + i * 16 + rq + r;
                int col = n0 + wn + j * 16 + cn;
                float v = acc[i][j][r];
                if (ep == 0) {
                    C[(size_t)row * ldc + col] = v;
                } else if (ep == 1) {
                    v += bias[col];
                    v = (v > 20.f) ? v : log1pf(__expf(v));
                    Cb[(size_t)row * ldc + col] = f2bf(v);
                } else {
                    Cb[(size_t)row * ldc + col] = f2bf(v);
                }
            }
        }
    }
}

// ---------------- out = x + sum_z part[z] ----------------
__global__ __launch_bounds__(256) void out_reduce(
    const float* __restrict__ part, const float* __restrict__ x,
    float* __restrict__ out)
{
    int i = blockIdx.x * 256 + threadIdx.x;
    float4 s = reinterpret_cast<const float4*>(x)[i];
    #pragma unroll
    for (int z = 0; z < 4; ++z) {
        float4 p = reinterpret_cast<const float4*>(part + (size_t)z * 2097152)[i];
        s.x += p.x; s.y += p.y; s.z += p.z; s.w += p.w;
    }
    reinterpret_cast<float4*>(out)[i] = s;
}

// ---------------- xproj split-K: A = u (bf16), B = w_xproj (fp32) ----------------
__global__ __launch_bounds__(256) void xproj_splitk(
    const unsigned short* __restrict__ A,
    const float* __restrict__ B,
    float* __restrict__ part)
{
    __shared__ float As[16][68];
    __shared__ float Bs[16][100];
    int tid = threadIdx.x;
    int m0 = blockIdx.x * 64;
    int k0 = blockIdx.y * 128;
    int tx = tid & 15;
    int ty = tid >> 4;
    float acc[4][6] = {};
    int arow = tid >> 2, akg = (tid & 3) << 2;
    int brow1 = (256 + tid) >> 2, bkg1 = ((256 + tid) & 3) << 2;

    for (int ks = 0; ks < 128; ks += 16) {
        ushort4 au = *reinterpret_cast<const ushort4*>(A + (size_t)(m0 + arow) * 2048 + k0 + ks + akg);
        float4 av = make_float4(bfb(au.x), bfb(au.y), bfb(au.z), bfb(au.w));
        float4 bv0 = make_float4(0.f, 0.f, 0.f, 0.f), bv1 = bv0;
        if (arow < 96)  bv0 = *reinterpret_cast<const float4*>(B + (size_t)arow * 2048 + k0 + ks + akg);
        if (brow1 < 96) bv1 = *reinterpret_cast<const float4*>(B + (size_t)brow1 * 2048 + k0 + ks + bkg1);
        __syncthreads();
        As[akg + 0][arow] = av.x; As[akg + 1][arow] = av.y;
        As[akg + 2][arow] = av.z; As[akg + 3][arow] = av.w;
        if (arow < 96) {
            Bs[akg + 0][arow] = bv0.x; Bs[akg + 1][arow] = bv0.y;
            Bs[akg + 2][arow] = bv0.z; Bs[akg + 3][arow] = bv0.w;
        }
        if (brow1 < 96) {
            Bs[bkg1 + 0][brow1] = bv1.x; Bs[bkg1 + 1][brow1] = bv1.y;
            Bs[bkg1 + 2][brow1] = bv1.z; Bs[bkg1 + 3][brow1] = bv1.w;
        }
        __syncthreads();
        #pragma unroll
        for (int k = 0; k < 16; ++k) {
            float aa[4], bb[6];
            #pragma unroll
            for (int i = 0; i < 4; ++i) aa[i] = As[k][ty * 4 + i];
            #pragma unroll
            for (int j = 0; j < 6; ++j) bb[j] = Bs[k][tx * 6 + j];
            #pragma unroll
            for (int i = 0; i < 4; ++i)
                #pragma unroll
                for (int j = 0; j < 6; ++j)
                    acc[i][j] = fmaf(aa[i], bb[j], acc[i][j]);
        }
    }
    float* p = part + (size_t)blockIdx.y * 196608;
    #pragma unroll
    for (int i = 0; i < 4; ++i)
        #pragma unroll
        for (int j = 0; j < 6; ++j)
            p[(size_t)(m0 + ty * 4 + i) * 96 + tx * 6 + j] = acc[i][j];
}

// reduce 16 partials -> xdbl fp32; also emit dt_r (cols<64) as bf16
__global__ __launch_bounds__(256) void xproj_reduce(
    const float* __restrict__ part, float* __restrict__ xdbl,
    unsigned short* __restrict__ dtr)
{
    int i = blockIdx.x * 256 + threadIdx.x;   // 196608
    float s = 0.f;
    #pragma unroll
    for (int sd = 0; sd < 16; ++sd) s += part[(size_t)sd * 196608 + i];
    xdbl[i] = s;
    int m = i / 96, col = i - m * 96;
    if (col < 64) dtr[(size_t)m * 64 + col] = f2bf(s);
}

// ---------------- Depthwise causal conv + SiLU: 2 consecutive l per thread ----------
__global__ __launch_bounds__(256) void conv_silu_kernel(
    const unsigned short* __restrict__ xz,
    const float* __restrict__ cw,
    const float* __restrict__ cb,
    unsigned short* __restrict__ u)
{
    int idx = blockIdx.x * 256 + threadIdx.x;   // 2,097,152
    int e = idx & 2047;
    int mp = idx >> 11;          // 0..1023
    int m0 = mp * 2;             // even row; l0 = m0 & 1023 even
    int l0 = m0 & 1023;
    float r[5];
    #pragma unroll
    for (int k = 0; k < 5; ++k) {
        int lr = l0 - 3 + k;
        r[k] = (lr >= 0) ? bfb(xz[(size_t)(m0 - 3 + k) * 4096 + e]) : 0.f;
    }
    float4 w = *reinterpret_cast<const float4*>(cw + e * 4);
    float base = cb[e];
    float a0 = base + w.x * r[0] + w.y * r[1] + w.z * r[2] + w.w * r[3];
    float a1 = base + w.x * r[1] + w.y * r[2] + w.z * r[3] + w.w * r[4];
    u[(size_t)m0 * 2048 + e]       = f2bf(siluf(a0));
    u[(size_t)(m0 + 1) * 2048 + e] = f2bf(siluf(a1));
}

// ---------------- Chunked selective scan: 4 states/lane, LC=16, 64 chunks ----------
// grid 4096 = (b:2) x (et:32) x (c:64); 256 threads = 64 channels x 4 ngroups.
// One-past-end prefetch lands in adjacent live ws regions - always in-bounds.
__global__ __launch_bounds__(256) void scan_part1(
    const unsigned short* __restrict__ dt,
    const unsigned short* __restrict__ u,
    const float* __restrict__ xdbl,
    const float* __restrict__ a_log,
    float* __restrict__ hpart,
    float* __restrict__ Aprod)
{
    int tid = threadIdx.x;
    int ch = tid >> 2, ng = tid & 3;
    int bid = blockIdx.x;
    int c = bid & 63, et = (bid >> 6) & 31, b = bid >> 11;
    int e = et * 64 + ch;
    float4 al = *reinterpret_cast<const float4*>(a_log + e * 16 + ng * 4);
    float A0 = -__expf(al.x), A1 = -__expf(al.y), A2 = -__expf(al.z), A3 = -__expf(al.w);
    size_t rbase = (size_t)b * 1024 + c * LC;
    const unsigned short* dt_p = dt + rbase * 2048 + e;
    const unsigned short* u_p  = u  + rbase * 2048 + e;
    const float* b_p  = xdbl + rbase * 96 + 64 + ng * 4;
    float h0 = 0.f, h1 = 0.f, h2 = 0.f, h3 = 0.f;
    float P0 = 1.f, P1 = 1.f, P2 = 1.f, P3 = 1.f;
    float dt_c = bfb(dt_p[0]);
    float u_c  = bfb(u_p[0]);
    float4 B_c = *reinterpret_cast<const float4*>(b_p);
    #pragma unroll 8
    for (int l = 0; l < LC; ++l) {
        float dt_n = bfb(dt_p[(size_t)(l + 1) * 2048]);
        float u_n  = bfb(u_p[(size_t)(l + 1) * 2048]);
        float4 B_n = *reinterpret_cast<const float4*>(b_p + (size_t)(l + 1) * 96);
        float du = dt_c * u_c;
        float d0 = __expf(dt_c * A0), d1 = __expf(dt_c * A1);
        float d2 = __expf(dt_c * A2), d3 = __expf(dt_c * A3);
        h0 = fmaf(d0, h0, du * B_c.x); P0 *= d0;
        h1 = fmaf(d1, h1, du * B_c.y); P1 *= d1;
        h2 = fmaf(d2, h2, du * B_c.z); P2 *= d2;
        h3 = fmaf(d3, h3, du * B_c.w); P3 *= d3;
        dt_c = dt_n; u_c = u_n; B_c = B_n;
    }
    size_t oidx = (size_t)c * 65536 + ((size_t)b * 2048 + e) * 16 + ng * 4;
    *reinterpret_cast<float4*>(hpart + oidx) = make_float4(h0, h1, h2, h3);
    *reinterpret_cast<float4*>(Aprod + oidx) = make_float4(P0, P1, P2, P3);
}

__global__ __launch_bounds__(256) void scan_combine(
    const float* __restrict__ hpart,
    const float* __restrict__ Aprod,
    float* __restrict__ hinit)
{
    int t = (blockIdx.x * 256 + threadIdx.x) * 4;   // 16384 threads x float4
    float4 h = make_float4(0.f, 0.f, 0.f, 0.f);
    #pragma unroll
    for (int c = 0; c < NCHUNK; ++c) {
        *reinterpret_cast<float4*>(hinit + (size_t)c * 65536 + t) = h;
        float4 P = *reinterpret_cast<const float4*>(Aprod + (size_t)c * 65536 + t);
        float4 hp = *reinterpret_cast<const float4*>(hpart + (size_t)c * 65536 + t);
        h.x = fmaf(P.x, h.x, hp.x);
        h.y = fmaf(P.y, h.y, hp.y);
        h.z = fmaf(P.z, h.z, hp.z);
        h.w = fmaf(P.w, h.w, hp.w);
    }
}

__global__ __launch_bounds__(256) void scan_part2(
    const unsigned short* __restrict__ dt,
    const unsigned short* __restrict__ u,
    const float* __restrict__ xdbl,
    const unsigned short* __restrict__ xz,
    const float* __restrict__ a_log,
    const float* __restrict__ d_skip,
    const float* __restrict__ hinit,
    unsigned short* __restrict__ y)
{
    int tid = threadIdx.x;
    int ch = tid >> 2, ng = tid & 3;
    int bid = blockIdx.x;
    int c = bid & 63, et = (bid >> 6) & 31, b = bid >> 11;
    int e = et * 64 + ch;
    float4 al = *reinterpret_cast<const float4*>(a_log + e * 16 + ng * 4);
    float A0 = -__expf(al.x), A1 = -__expf(al.y), A2 = -__expf(al.z), A3 = -__expf(al.w);
    float dsk = d_skip[e];
    size_t rbase = (size_t)b * 1024 + c * LC;
    const unsigned short* dt_p = dt + rbase * 2048 + e;
    const unsigned short* u_p  = u  + rbase * 2048 + e;
    const unsigned short* z_p  = xz + rbase * 4096 + 2048 + e;
    const float* bc_p = xdbl + rbase * 96 + 64 + ng * 4;
    unsigned short* y_p = y + rbase * 2048 + e;
    size_t oidx = (size_t)c * 65536 + ((size_t)b * 2048 + e) * 16 + ng * 4;
    float4 hi = *reinterpret_cast<const float4*>(hinit + oidx);
    float h0 = hi.x, h1 = hi.y, h2 = hi.z, h3 = hi.w;
    float dt_c = bfb(dt_p[0]);
    float u_c  = bfb(u_p[0]);
    float4 B_c = *reinterpret_cast<const float4*>(bc_p);
    float4 C_c = *reinterpret_cast<const float4*>(bc_p + 16);
    #pragma unroll 8
    for (int l = 0; l < LC; ++l) {
        float dt_n = bfb(dt_p[(size_t)(l + 1) * 2048]);
        float u_n  = bfb(u_p[(size_t)(l + 1) * 2048]);
        float4 B_n = *reinterpret_cast<const float4*>(bc_p + (size_t)(l + 1) * 96);
        float4 C_n = *reinterpret_cast<const float4*>(bc_p + (size_t)(l + 1) * 96 + 16);
        float du = dt_c * u_c;
        float d0 = __expf(dt_c * A0), d1 = __expf(dt_c * A1);
        float d2 = __expf(dt_c * A2), d3 = __expf(dt_c * A3);
        h0 = fmaf(d0, h0, du * B_c.x);
        h1 = fmaf(d1, h1, du * B_c.y);
        h2 = fmaf(d2, h2, du * B_c.z);
        h3 = fmaf(d3, h3, du * B_c.w);
        float p = h0 * C_c.x + h1 * C_c.y + h2 * C_c.z + h3 * C_c.w;
        p += __shfl_xor(p, 1);
        p += __shfl_xor(p, 2);
        if (ng == 0) {
            float zv = bfb(z_p[(size_t)l * 4096]);
            y_p[(size_t)l * 2048] = f2bf((p + u_c * dsk) * siluf(zv));
        }
        dt_c = dt_n; u_c = u_n; B_c = B_n; C_c = C_n;
    }
}

extern "C" void kernel_launch(void* const* d_in, const int* in_sizes, int n_in,
                              void* d_out, int out_size, void* d_ws, size_t ws_size,
                              hipStream_t stream) {
    const float* x       = (const float*)d_in[0];
    const float* ln_w    = (const float*)d_in[1];
    const float* ln_b    = (const float*)d_in[2];
    const float* w_in    = (const float*)d_in[3];
    const float* conv_w  = (const float*)d_in[4];
    const float* conv_b  = (const float*)d_in[5];
    const float* w_xproj = (const float*)d_in[6];
    const float* w_dt    = (const float*)d_in[7];
    const float* b_dt    = (const float*)d_in[8];
    const float* a_log   = (const float*)d_in[9];
    const float* d_skip  = (const float*)d_in[10];
    const float* w_out   = (const float*)d_in[11];
    float* out = (float*)d_out;

    float* ws = (float*)d_ws;
    unsigned short* xn_b    = (unsigned short*)(ws);
    unsigned short* xz_b    = (unsigned short*)(ws + 1048576);
    unsigned short* u_b     = (unsigned short*)(ws + 5242880);
    float* xdbl  = ws + 7340032;
    unsigned short* dt_b    = (unsigned short*)(ws + 7536640);
    float* hpart = ws + 9633792;    // 4M
    float* Aprod = ws + 13828096;   // 4M
    float* hinit = ws + 18022400;   // 4M
    unsigned short* y_b     = (unsigned short*)(ws + 22216704);
    unsigned short* w_in_b  = (unsigned short*)(ws + 24313856);
    unsigned short* w_out_b = (unsigned short*)(ws + 26411008);
    unsigned short* w_dt_b  = (unsigned short*)(ws + 27459584);
    unsigned short* dtr_b   = (unsigned short*)(ws + 27525120);
    float* xpart = ws + 9633792;    // aliases hpart (dead until scan)
    float* opart = ws + 1048576;    // aliases xz_b..dt_b (dead after part2)

    // 0. weight converts + LayerNorm, one launch
    setup_kernel<<<8320, 256, 0, stream>>>(w_in, w_in_b, w_out, w_out_b, w_dt, w_dt_b,
                                           x, ln_w, ln_b, xn_b);
    // 1. xz = xn @ w_in^T  (2048 x 4096 x 1024)  MFMA -> bf16
    gemm_bf16_nt<<<dim3(64, 16, 1), 256, 0, stream>>>(xn_b, 1024, w_in_b, 1024, 1024,
                                                      nullptr, xz_b, 4096, nullptr, 3, 0);
    // 2. depthwise conv + silu -> u (bf16), 2 l per thread
    conv_silu_kernel<<<8192, 256, 0, stream>>>(xz_b, conv_w, conv_b, u_b);
    // 3. x_dbl = u @ w_xproj^T  (2048 x 96 x 2048)  fp32 split-K (A bf16)
    xproj_splitk<<<dim3(32, 16), 256, 0, stream>>>(u_b, w_xproj, xpart);
    xproj_reduce<<<768, 256, 0, stream>>>(xpart, xdbl, dtr_b);
    // 4. dt = softplus(dt_r @ w_dt^T + b_dt)  MFMA -> bf16
    gemm_bf16_nt<<<dim3(32, 16, 1), 256, 0, stream>>>(dtr_b, 64, w_dt_b, 64, 64,
                                                      nullptr, dt_b, 2048, b_dt, 1, 0);
    // 5. chunked selective scan (LC=16, 64 chunks) -> y (bf16)
    scan_part1<<<4096, 256, 0, stream>>>(dt_b, u_b, xdbl, a_log, hpart, Aprod);
    scan_combine<<<64, 256, 0, stream>>>(hpart, Aprod, hinit);
    scan_part2<<<4096, 256, 0, stream>>>(dt_b, u_b, xdbl, xz_b, a_log, d_skip, hinit, y_b);
    // 6. out-proj split-K x4 (fp32 partials) + reduce(+residual)
    gemm_bf16_nt<<<dim3(16, 16, 4), 256, 0, stream>>>(y_b, 2048, w_out_b, 2048, 512,
                                                      opart, nullptr, 1024, nullptr, 0, 2097152);
    out_reduce<<<2048, 256, 0, stream>>>(opart, x, out);
}